// Round 3
// baseline (145.030 us; speedup 1.0000x reference)
//
#include <hip/hip_runtime.h>

// Problem constants
#define NSEG   4480     // 70 * 64
#define ADIM   64
#define BDIM   16
#define NEDGE  65536
#define DPB    16       // destinations (output rows) per block
#define NBLK   (NSEG / DPB)   // 280 blocks
#define TPB    256      // 4 waves
#define CAPL   64       // LDS bucket capacity per dst (Poisson mean 14.6, max ~30)
#define GSP    1096     // Gs pitch in bf16 elems: 1088 + 8 pad (2192 B = 548 dw = 4 mod 32
                        //  -> A-frag ds_read_b128 bank-uniform)

// Single fused kernel, ONE dispatch. R2's 4-dispatch chain cost ~58 us for
// ~15 us of work: ~10 us/dispatch serial overhead + 24 MB of G/eb global
// round-trips across L2-flush kernel boundaries. Here every intermediate
// lives in LDS; blocks are fully independent (each finds its own edges by
// scanning pair[], which is L2-resident), so no grid sync, no memset, no
// workspace use at all.
//
// Per block (owns dsts [dlo, dlo+16)):
//   phase 1: scan all 65536 edges (int4 = 2 edges/load, coalesced), bucket
//            {edge, src} of mine into LDS (LDS atomics; ~234 hits/block).
//   phase 2: accum G[d, r*64+j] = sum_e bond[e,r]*atom[src_e, j] (r<16),
//            G[d, 16*64+j] = sum_e atom[src_e, j] (bias slice). Wave w owns
//            dsts w*4..w*4+3 as 2 interleaved streams (MLP=2 on the
//            bucket->atom dep chain); exact f32 accum, one bf16 rounding.
//   phase 3: out[16,64] = G[16,1088] @ K2[1088,64] via mfma_16x16x32_bf16.
//            K2[r*64+j, c] = kern[r, c*64+j] (r<16), bias[c*64+j] (r=16):
//            each lane's B-frag is 8 CONTIGUOUS floats of kern -> loaded
//            straight to registers, converted to bf16 in-reg. No B staging,
//            no barriers in the K loop, 34 independent global loads/wave.
// LDS: 16*1096*2 + 16*64*8 + 64 = 43.3 KB -> 3 blocks/CU, 12 waves/CU.

typedef __bf16 bf16x8 __attribute__((ext_vector_type(8)));
typedef float  f32x4  __attribute__((ext_vector_type(4)));

__device__ __forceinline__ unsigned short f2bf(float f) {
    union { float f; unsigned int i; } c; c.f = f;
    unsigned int x = c.i;
    x += 0x7fffu + ((x >> 16) & 1u);   // round-to-nearest-even
    return (unsigned short)(x >> 16);
}

union U8 { unsigned short u[8]; bf16x8 v; };

__device__ __forceinline__ bf16x8 pack_bf8(float4 a, float4 b) {
    U8 r;
    r.u[0] = f2bf(a.x); r.u[1] = f2bf(a.y); r.u[2] = f2bf(a.z); r.u[3] = f2bf(a.w);
    r.u[4] = f2bf(b.x); r.u[5] = f2bf(b.y); r.u[6] = f2bf(b.z); r.u[7] = f2bf(b.w);
    return r.v;
}

__global__ __launch_bounds__(TPB) void fused_kernel(
    const float* __restrict__ atom,    // [4480, 64]  f32
    const float* __restrict__ bond,    // [65536, 16] f32
    const int*   __restrict__ pair,    // [65536, 2]  int32 {dst, src}
    const float* __restrict__ kern,    // [16, 4096]  f32
    const float* __restrict__ bias,    // [4096]      f32
    float*       __restrict__ out)     // [4480, 64]  f32
{
    __shared__ int  bcnt[DPB];
    __shared__ int2 ebuf[DPB][CAPL];               // {edge, src}
    __shared__ unsigned short Gs[DPB * GSP];       // bf16 G tile

    const int t   = threadIdx.x;
    const int dlo = blockIdx.x * DPB;

    if (t < DPB) bcnt[t] = 0;
    __syncthreads();

    // ---- phase 1: scan + LDS bucket ------------------------------------
    {
        const int4* p4 = (const int4*)pair;        // {dst0,src0,dst1,src1}
        for (int i = t; i < NEDGE / 2; i += TPB) {
            const int4 pp = p4[i];
            const unsigned d0 = (unsigned)(pp.x - dlo);
            if (d0 < DPB) {
                const int ix = atomicAdd(&bcnt[d0], 1);
                if (ix < CAPL) ebuf[d0][ix] = make_int2(2 * i, pp.y);
            }
            const unsigned d1 = (unsigned)(pp.z - dlo);
            if (d1 < DPB) {
                const int ix = atomicAdd(&bcnt[d1], 1);
                if (ix < CAPL) ebuf[d1][ix] = make_int2(2 * i + 1, pp.w);
            }
        }
    }
    __syncthreads();

    const int lane = t & 63;
    const int w    = t >> 6;                       // wave 0..3

    // ---- phase 2: per-dst outer-product accumulation into Gs -----------
#pragma unroll
    for (int pi = 0; pi < 2; ++pi) {
        const int da = w * 4 + pi * 2;             // two interleaved streams
        const int db = da + 1;
        int na = bcnt[da]; na = na < CAPL ? na : CAPL;
        int nb = bcnt[db]; nb = nb < CAPL ? nb : CAPL;
        float ga[17], gb[17];
#pragma unroll
        for (int r = 0; r < 17; ++r) { ga[r] = 0.f; gb[r] = 0.f; }
        const int n = na > nb ? na : nb;
        for (int k = 0; k < n; ++k) {
            if (k < na) {                          // wave-uniform branch
                const int2 es = ebuf[da][k];
                const float a = atom[(size_t)es.y * ADIM + lane];
                const float4* bp = (const float4*)(bond + (size_t)es.x * BDIM);
                const float4 c0 = bp[0], c1 = bp[1], c2 = bp[2], c3 = bp[3];
                const float bb[16] = { c0.x,c0.y,c0.z,c0.w, c1.x,c1.y,c1.z,c1.w,
                                       c2.x,c2.y,c2.z,c2.w, c3.x,c3.y,c3.z,c3.w };
#pragma unroll
                for (int r = 0; r < 16; ++r) ga[r] = fmaf(a, bb[r], ga[r]);
                ga[16] += a;
            }
            if (k < nb) {
                const int2 es = ebuf[db][k];
                const float a = atom[(size_t)es.y * ADIM + lane];
                const float4* bp = (const float4*)(bond + (size_t)es.x * BDIM);
                const float4 c0 = bp[0], c1 = bp[1], c2 = bp[2], c3 = bp[3];
                const float bb[16] = { c0.x,c0.y,c0.z,c0.w, c1.x,c1.y,c1.z,c1.w,
                                       c2.x,c2.y,c2.z,c2.w, c3.x,c3.y,c3.z,c3.w };
#pragma unroll
                for (int r = 0; r < 16; ++r) gb[r] = fmaf(a, bb[r], gb[r]);
                gb[16] += a;
            }
        }
        // lane j writes G[d, r*64+j]: 128 B contiguous per r, 2-way banks (free)
#pragma unroll
        for (int r = 0; r < 17; ++r) {
            Gs[da * GSP + r * 64 + lane] = f2bf(ga[r]);
            Gs[db * GSP + r * 64 + lane] = f2bf(gb[r]);
        }
    }
    __syncthreads();

    // ---- phase 3: out = Gs @ K2 (MFMA, B direct from global) -----------
    // Fragment layouts (m89/m91-verified): A: row=lane&15, k=quad*8+j;
    // B: col=lane&15, k=quad*8+j; D: col=lane&15, row=quad*4+reg.
    const int m    = lane & 15;
    const int quad = lane >> 4;
    const int c    = w * 16 + m;                   // output col (B col n)

    f32x4 acc = {0.f, 0.f, 0.f, 0.f};
#pragma unroll 4
    for (int r = 0; r < 16; ++r) {
        const float* ks = kern + (size_t)r * 4096 + (size_t)c * 64;
        const float4* kp = (const float4*)(ks + quad * 8);
        const float4* kq = (const float4*)(ks + 32 + quad * 8);
        const float4 x0 = kp[0], x1 = kp[1];
        const float4 y0 = kq[0], y1 = kq[1];
        const bf16x8 a0 = *(const bf16x8*)(Gs + m * GSP + r * 64 + quad * 8);
        const bf16x8 a1 = *(const bf16x8*)(Gs + m * GSP + r * 64 + 32 + quad * 8);
        acc = __builtin_amdgcn_mfma_f32_16x16x32_bf16(a0, pack_bf8(x0, x1), acc, 0, 0, 0);
        acc = __builtin_amdgcn_mfma_f32_16x16x32_bf16(a1, pack_bf8(y0, y1), acc, 0, 0, 0);
    }
    {   // bias slice (r = 16)
        const float* ks = bias + (size_t)c * 64;
        const float4* kp = (const float4*)(ks + quad * 8);
        const float4* kq = (const float4*)(ks + 32 + quad * 8);
        const float4 x0 = kp[0], x1 = kp[1];
        const float4 y0 = kq[0], y1 = kq[1];
        const bf16x8 a0 = *(const bf16x8*)(Gs + m * GSP + 16 * 64 + quad * 8);
        const bf16x8 a1 = *(const bf16x8*)(Gs + m * GSP + 16 * 64 + 32 + quad * 8);
        acc = __builtin_amdgcn_mfma_f32_16x16x32_bf16(a0, pack_bf8(x0, x1), acc, 0, 0, 0);
        acc = __builtin_amdgcn_mfma_f32_16x16x32_bf16(a1, pack_bf8(y0, y1), acc, 0, 0, 0);
    }

    // D: row = dlo + quad*4 + rr, col = c. Every out row/col written once.
#pragma unroll
    for (int rr = 0; rr < 4; ++rr)
        out[(size_t)(dlo + quad * 4 + rr) * ADIM + c] = acc[rr];
}

extern "C" void kernel_launch(void* const* d_in, const int* in_sizes, int n_in,
                              void* d_out, int out_size, void* d_ws, size_t ws_size,
                              hipStream_t stream) {
    const float* atom = (const float*)d_in[0];
    const float* bond = (const float*)d_in[1];
    const int*   pair = (const int*)  d_in[2];
    const float* kern = (const float*)d_in[3];
    const float* bias = (const float*)d_in[4];
    float* out = (float*)d_out;

    fused_kernel<<<NBLK, TPB, 0, stream>>>(atom, bond, pair, kern, bias, out);
}

// Round 4
// 111.378 us; speedup vs baseline: 1.3021x; 1.3021x over previous
//
#include <hip/hip_runtime.h>

// Problem constants
#define NSEG   4480     // 70 * 64
#define ADIM   64
#define BDIM   16
#define NEDGE  65536
#define DPB    32       // destinations (output rows) per block
#define NBLK   (NSEG / DPB)   // 140 blocks -> all resident (1 block/CU), no tail
#define TPB    1024     // 16 waves -> 4 waves/SIMD (R3 had 1/SIMD = the failure)
#define CAPL   64       // LDS bucket capacity per dst (Poisson mean 14.6, max ~30)
#define GSP    1096     // Gs pitch in bf16 elems: 1088 + 8 pad (548 dw = 4 mod 32)

// ONE dispatch (R2: 5 dispatches = ~58 us wall for ~15 us work; R3: fused but
// 1 wave/SIMD latency-starved = 90 us, Occ 11% / VALU 6.5% / HBM 1.4%).
// Shape fixes vs R3: 1024-thr blocks (4 waves/SIMD), 32-iteration unrolled
// scan (>=4 loads in flight), DPB=32 halves aggregate scan traffic, 140
// blocks all co-resident.
//
// Per block (owns dsts [dlo, dlo+32)):
//   phase 1: scan pair[] (int4 = 2 edges/load, 16 KB/block/iter coalesced),
//            bucket {edge, src} of mine into LDS (~470 LDS-atomic hits).
//   phase 2: wave w accums dsts {2w, 2w+1} as 2 interleaved streams:
//            G[d, r*64+j] = sum_e bond[e,r] * atom[src_e, j]  (r < 16)
//            G[d, 16*64+j] = sum_e atom[src_e, j]             (bias slice)
//            exact f32 accum, single bf16 rounding into LDS Gs.
//   phase 3: waves 0..7: out[32,64] = Gs[32,1088] @ K2[1088,64] via
//            mfma_16x16x32_bf16; wave w -> (mt = w>>2, ct = w&3).
//            K2[r*64+j, c] = kern[r, c*64+j] (r<16) / bias[c*64+j] (r=16):
//            each lane's B-frag is 8 CONTIGUOUS kern floats -> registers,
//            no LDS staging, no barriers in the K loop.
// LDS: 128 + 16384 + 70144 = 86.7 KB -> 1 block/CU, 16 waves/CU.

typedef __bf16 bf16x8 __attribute__((ext_vector_type(8)));
typedef float  f32x4  __attribute__((ext_vector_type(4)));

__device__ __forceinline__ unsigned short f2bf(float f) {
    union { float f; unsigned int i; } c; c.f = f;
    unsigned int x = c.i;
    x += 0x7fffu + ((x >> 16) & 1u);   // round-to-nearest-even
    return (unsigned short)(x >> 16);
}

union U8 { unsigned short u[8]; bf16x8 v; };

__device__ __forceinline__ bf16x8 pack_bf8(float4 a, float4 b) {
    U8 r;
    r.u[0] = f2bf(a.x); r.u[1] = f2bf(a.y); r.u[2] = f2bf(a.z); r.u[3] = f2bf(a.w);
    r.u[4] = f2bf(b.x); r.u[5] = f2bf(b.y); r.u[6] = f2bf(b.z); r.u[7] = f2bf(b.w);
    return r.v;
}

__global__ __launch_bounds__(TPB) void fused_kernel(
    const float* __restrict__ atom,    // [4480, 64]  f32
    const float* __restrict__ bond,    // [65536, 16] f32
    const int*   __restrict__ pair,    // [65536, 2]  int32 {dst, src}
    const float* __restrict__ kern,    // [16, 4096]  f32
    const float* __restrict__ bias,    // [4096]      f32
    float*       __restrict__ out)     // [4480, 64]  f32
{
    __shared__ int  bcnt[DPB];
    __shared__ int2 ebuf[DPB][CAPL];               // {edge, src}
    __shared__ unsigned short Gs[DPB * GSP];       // bf16 G tile

    const int t   = threadIdx.x;
    const int dlo = blockIdx.x * DPB;

    if (t < DPB) bcnt[t] = 0;
    __syncthreads();

    // ---- phase 1: scan + LDS bucket (32 iters, unrolled for MLP) --------
    {
        const int4* p4 = (const int4*)pair;        // {dst0,src0,dst1,src1}
#pragma unroll 4
        for (int i = 0; i < NEDGE / 2 / TPB; ++i) {
            const int  ix4 = i * TPB + t;
            const int4 pp  = p4[ix4];
            const unsigned d0 = (unsigned)(pp.x - dlo);
            if (d0 < DPB) {
                const int ix = atomicAdd(&bcnt[d0], 1);
                if (ix < CAPL) ebuf[d0][ix] = make_int2(2 * ix4, pp.y);
            }
            const unsigned d1 = (unsigned)(pp.z - dlo);
            if (d1 < DPB) {
                const int ix = atomicAdd(&bcnt[d1], 1);
                if (ix < CAPL) ebuf[d1][ix] = make_int2(2 * ix4 + 1, pp.w);
            }
        }
    }
    __syncthreads();

    const int lane = t & 63;
    const int w    = t >> 6;                       // wave 0..15

    // ---- phase 2: per-dst outer-product accumulation into Gs -----------
    {
        const int da = 2 * w;                      // two interleaved streams
        const int db = 2 * w + 1;
        int na = bcnt[da]; na = na < CAPL ? na : CAPL;
        int nb = bcnt[db]; nb = nb < CAPL ? nb : CAPL;
        float ga[17], gb[17];
#pragma unroll
        for (int r = 0; r < 17; ++r) { ga[r] = 0.f; gb[r] = 0.f; }
        const int n = na > nb ? na : nb;
        for (int k = 0; k < n; ++k) {
            if (k < na) {                          // wave-uniform branch
                const int2 es = ebuf[da][k];
                const float a = atom[(size_t)es.y * ADIM + lane];
                const float4* bp = (const float4*)(bond + (size_t)es.x * BDIM);
                const float4 c0 = bp[0], c1 = bp[1], c2 = bp[2], c3 = bp[3];
                const float bb[16] = { c0.x,c0.y,c0.z,c0.w, c1.x,c1.y,c1.z,c1.w,
                                       c2.x,c2.y,c2.z,c2.w, c3.x,c3.y,c3.z,c3.w };
#pragma unroll
                for (int r = 0; r < 16; ++r) ga[r] = fmaf(a, bb[r], ga[r]);
                ga[16] += a;
            }
            if (k < nb) {
                const int2 es = ebuf[db][k];
                const float a = atom[(size_t)es.y * ADIM + lane];
                const float4* bp = (const float4*)(bond + (size_t)es.x * BDIM);
                const float4 c0 = bp[0], c1 = bp[1], c2 = bp[2], c3 = bp[3];
                const float bb[16] = { c0.x,c0.y,c0.z,c0.w, c1.x,c1.y,c1.z,c1.w,
                                       c2.x,c2.y,c2.z,c2.w, c3.x,c3.y,c3.z,c3.w };
#pragma unroll
                for (int r = 0; r < 16; ++r) gb[r] = fmaf(a, bb[r], gb[r]);
                gb[16] += a;
            }
        }
        // lane j writes G[d, r*64+j]: 128 B contiguous per r, 2 lanes/bank (free)
#pragma unroll
        for (int r = 0; r < 17; ++r) {
            Gs[da * GSP + r * 64 + lane] = f2bf(ga[r]);
            Gs[db * GSP + r * 64 + lane] = f2bf(gb[r]);
        }
    }
    __syncthreads();

    // ---- phase 3: out = Gs @ K2 (MFMA, B direct from global) -----------
    // Fragment layouts (m89/m91-verified, R2/R3-passed): A: row=lane&15,
    // k=quad*8+j; B: col=lane&15, k=quad*8+j; D: col=lane&15, row=quad*4+reg.
    if (w < 8) {
        const int mt   = w >> 2;                   // M tile 0/1
        const int ct   = w & 3;                    // N tile 0..3
        const int m    = lane & 15;
        const int quad = lane >> 4;
        const int c    = ct * 16 + m;              // output col (B col n)
        const unsigned short* Ga = Gs + (size_t)(mt * 16 + m) * GSP;

        f32x4 acc = {0.f, 0.f, 0.f, 0.f};
#pragma unroll 4
        for (int r = 0; r < 16; ++r) {
            const float* ks = kern + (size_t)r * 4096 + (size_t)c * 64;
            const float4* kp = (const float4*)(ks + quad * 8);
            const float4* kq = (const float4*)(ks + 32 + quad * 8);
            const float4 x0 = kp[0], x1 = kp[1];
            const float4 y0 = kq[0], y1 = kq[1];
            const bf16x8 a0 = *(const bf16x8*)(Ga + r * 64 + quad * 8);
            const bf16x8 a1 = *(const bf16x8*)(Ga + r * 64 + 32 + quad * 8);
            acc = __builtin_amdgcn_mfma_f32_16x16x32_bf16(a0, pack_bf8(x0, x1), acc, 0, 0, 0);
            acc = __builtin_amdgcn_mfma_f32_16x16x32_bf16(a1, pack_bf8(y0, y1), acc, 0, 0, 0);
        }
        {   // bias slice (r = 16)
            const float* ks = bias + (size_t)c * 64;
            const float4* kp = (const float4*)(ks + quad * 8);
            const float4* kq = (const float4*)(ks + 32 + quad * 8);
            const float4 x0 = kp[0], x1 = kp[1];
            const float4 y0 = kq[0], y1 = kq[1];
            const bf16x8 a0 = *(const bf16x8*)(Ga + 16 * 64 + quad * 8);
            const bf16x8 a1 = *(const bf16x8*)(Ga + 16 * 64 + 32 + quad * 8);
            acc = __builtin_amdgcn_mfma_f32_16x16x32_bf16(a0, pack_bf8(x0, x1), acc, 0, 0, 0);
            acc = __builtin_amdgcn_mfma_f32_16x16x32_bf16(a1, pack_bf8(y0, y1), acc, 0, 0, 0);
        }

        // D: row = dlo + mt*16 + quad*4 + rr, col = c. Every row written once.
#pragma unroll
        for (int rr = 0; rr < 4; ++rr)
            out[(size_t)(dlo + mt * 16 + quad * 4 + rr) * ADIM + c] = acc[rr];
    }
}

extern "C" void kernel_launch(void* const* d_in, const int* in_sizes, int n_in,
                              void* d_out, int out_size, void* d_ws, size_t ws_size,
                              hipStream_t stream) {
    const float* atom = (const float*)d_in[0];
    const float* bond = (const float*)d_in[1];
    const int*   pair = (const int*)  d_in[2];
    const float* kern = (const float*)d_in[3];
    const float* bias = (const float*)d_in[4];
    float* out = (float*)d_out;

    fused_kernel<<<NBLK, TPB, 0, stream>>>(atom, bond, pair, kern, bias, out);
}

// Round 5
// 92.192 us; speedup vs baseline: 1.5731x; 1.2081x over previous
//
#include <hip/hip_runtime.h>

// Problem constants
#define NSEG   4480     // 70 * 64
#define ADIM   64
#define BDIM   16
#define NEDGE  65536
#define DPB    16       // destinations (output rows) per fused block
#define NBLK   (NSEG / DPB)   // 280 blocks
#define TPB    1024     // 16 waves: one dst per wave (4480 waves total)
#define CAP    64       // bucket capacity per dst (Poisson mean 14.6, max ~35)
#define GSP    1096     // Gs pitch in bf16 elems: 1088 + 8 pad

// 3 dispatches. R4's single fused kernel was 52 us: every block re-scanned
// all 64k edges (32 serial L2 loads/wave) and phase 2 chained LDS->global
// per edge -- Occ 18%, VALU 10%, HBM 3% = pure latency starvation. Here the
// bucketing is done ONCE edge-parallel (65k threads), and the fused kernel
// gets its edges from global buckets: per wave ONE coalesced bucket load,
// then readlane-broadcast {edge,src} -> uniform (scalar) bond/atom
// addresses, 2-edge unroll for MLP. 4480 waves, ~4.4 waves/SIMD.
//
// Workspace: eb @ 0 : 4480*64*8 = 2,293,760 B {edge,src} buckets
//            cnt @ 4 MiB : 4480*4 B counters (memset each iteration)
#define CNT_OFF  (4u << 20)

typedef __bf16 bf16x8 __attribute__((ext_vector_type(8)));
typedef float  f32x4  __attribute__((ext_vector_type(4)));

__device__ __forceinline__ unsigned short f2bf(float f) {
    union { float f; unsigned int i; } c; c.f = f;
    unsigned int x = c.i;
    x += 0x7fffu + ((x >> 16) & 1u);   // round-to-nearest-even
    return (unsigned short)(x >> 16);
}

union U8 { unsigned short u[8]; bf16x8 v; };

__device__ __forceinline__ bf16x8 pack_bf8(float4 a, float4 b) {
    U8 r;
    r.u[0] = f2bf(a.x); r.u[1] = f2bf(a.y); r.u[2] = f2bf(a.z); r.u[3] = f2bf(a.w);
    r.u[4] = f2bf(b.x); r.u[5] = f2bf(b.y); r.u[6] = f2bf(b.z); r.u[7] = f2bf(b.w);
    return r.v;
}

// ---------------------------------------------------------------------------
// scatter_kernel: edge-parallel bucketing. One coalesced int2 load, one
// atomicAdd on the 17.9 KB L2-resident counter array (avg 14.6 hits/ctr),
// one 8 B bucket store. 65536 threads -> latency fully hidden by TLP.
// ---------------------------------------------------------------------------
__global__ __launch_bounds__(256) void scatter_kernel(
    const int* __restrict__ pair, int* __restrict__ cnt, int2* __restrict__ eb)
{
    const int e  = blockIdx.x * 256 + threadIdx.x;
    const int2 p = ((const int2*)pair)[e];          // .x = dst, .y = src
    const int idx = atomicAdd(&cnt[p.x], 1);
    if (idx < CAP) eb[(size_t)p.x * CAP + idx] = make_int2(e, p.y);
}

// ---------------------------------------------------------------------------
// fused_kernel: per block (16 dsts):
//   phase A (16 waves, one dst each): g[r] = sum_e bond[e,r]*atom[src_e,:]
//     (r<16), g[16] = sum_e atom[src_e,:]. Bucket loaded ONCE (lane l holds
//     entry l), readlane gives wave-uniform {e,src} -> scalar-load bond row
//     and atom base; 2-edge unroll = 2 independent load pairs in flight.
//     Exact f32 accum, single bf16 rounding into LDS Gs.
//   phase B (waves 0-3): out[16,64] = Gs[16,1088] @ K2[1088,64] via
//     mfma_16x16x32_bf16, software-pipelined (r+1 kern loads before r's
//     MFMAs). K2[r*64+j, c] = kern[r, c*64+j] / bias[c*64+j]: each lane's
//     B-frag is 8 contiguous kern floats -> registers, packed to bf16.
// Fragment layouts (m89/m91-verified, passed R2-R4): A: row=lane&15,
// k=quad*8+j; B: col=lane&15, k=quad*8+j; D: col=lane&15, row=quad*4+reg.
// LDS: 16*1096*2 = 35 KB.
// ---------------------------------------------------------------------------
__global__ __launch_bounds__(TPB) void fused_kernel(
    const float* __restrict__ atom,    // [4480, 64]  f32
    const float* __restrict__ bond,    // [65536, 16] f32
    const int*   __restrict__ cnt,     // [4480]
    const int2*  __restrict__ eb,      // [4480, 64] {edge, src}
    const float* __restrict__ kern,    // [16, 4096]  f32
    const float* __restrict__ bias,    // [4096]      f32
    float*       __restrict__ out)     // [4480, 64]  f32
{
    __shared__ unsigned short Gs[DPB * GSP];       // bf16 G tile

    const int t    = threadIdx.x;
    const int lane = t & 63;
    const int w    = t >> 6;                       // wave 0..15
    const int dlo  = blockIdx.x * DPB;
    const int d    = dlo + w;                      // this wave's dst

    // ---- phase A: accumulate this dst's outer products ------------------
    {
        int n = cnt[d];                            // uniform scalar load
        n = n < CAP ? n : CAP;
        const int2 my = eb[(size_t)d * CAP + lane];  // lane l = entry l (512 B/wave)

        float g[17];
#pragma unroll
        for (int r = 0; r < 17; ++r) g[r] = 0.f;

        int k = 0;
        for (; k + 2 <= n; k += 2) {
            const int e0 = __builtin_amdgcn_readlane(my.x, k);
            const int s0 = __builtin_amdgcn_readlane(my.y, k);
            const int e1 = __builtin_amdgcn_readlane(my.x, k + 1);
            const int s1 = __builtin_amdgcn_readlane(my.y, k + 1);
            const float a0 = atom[(size_t)s0 * ADIM + lane];
            const float a1 = atom[(size_t)s1 * ADIM + lane];
            const float4* b0p = (const float4*)(bond + (size_t)e0 * BDIM);
            const float4* b1p = (const float4*)(bond + (size_t)e1 * BDIM);
            const float4 c0 = b0p[0], c1 = b0p[1], c2 = b0p[2], c3 = b0p[3];
            const float4 d0 = b1p[0], d1 = b1p[1], d2 = b1p[2], d3 = b1p[3];
            const float bb0[16] = { c0.x,c0.y,c0.z,c0.w, c1.x,c1.y,c1.z,c1.w,
                                    c2.x,c2.y,c2.z,c2.w, c3.x,c3.y,c3.z,c3.w };
            const float bb1[16] = { d0.x,d0.y,d0.z,d0.w, d1.x,d1.y,d1.z,d1.w,
                                    d2.x,d2.y,d2.z,d2.w, d3.x,d3.y,d3.z,d3.w };
#pragma unroll
            for (int r = 0; r < 16; ++r) g[r] = fmaf(a0, bb0[r], g[r]);
            g[16] += a0;
#pragma unroll
            for (int r = 0; r < 16; ++r) g[r] = fmaf(a1, bb1[r], g[r]);
            g[16] += a1;
        }
        if (k < n) {
            const int e0 = __builtin_amdgcn_readlane(my.x, k);
            const int s0 = __builtin_amdgcn_readlane(my.y, k);
            const float a0 = atom[(size_t)s0 * ADIM + lane];
            const float4* b0p = (const float4*)(bond + (size_t)e0 * BDIM);
            const float4 c0 = b0p[0], c1 = b0p[1], c2 = b0p[2], c3 = b0p[3];
            const float bb0[16] = { c0.x,c0.y,c0.z,c0.w, c1.x,c1.y,c1.z,c1.w,
                                    c2.x,c2.y,c2.z,c2.w, c3.x,c3.y,c3.z,c3.w };
#pragma unroll
            for (int r = 0; r < 16; ++r) g[r] = fmaf(a0, bb0[r], g[r]);
            g[16] += a0;
        }

        // lane j writes G[w, r*64+j]: 128 B contiguous per r (2 lanes/bank, free)
#pragma unroll
        for (int r = 0; r < 17; ++r)
            Gs[w * GSP + r * 64 + lane] = f2bf(g[r]);
    }
    __syncthreads();

    // ---- phase B: out = Gs @ K2, software-pipelined ----------------------
    if (w < 4) {
        const int m    = lane & 15;
        const int quad = lane >> 4;
        const int c    = w * 16 + m;               // output col (B col n)
        const unsigned short* Ga = Gs + (size_t)m * GSP;

        f32x4 acc = {0.f, 0.f, 0.f, 0.f};

        const float* ks0 = kern + (size_t)c * 64 + quad * 8;
        float4 x0 = *(const float4*)(ks0);
        float4 x1 = *(const float4*)(ks0 + 4);
        float4 y0 = *(const float4*)(ks0 + 32);
        float4 y1 = *(const float4*)(ks0 + 36);

#pragma unroll
        for (int r = 0; r < 17; ++r) {
            float4 nx0, nx1, ny0, ny1;
            if (r + 1 < 17) {                      // issue next slice's loads
                const float* ns = ((r + 1 < 16) ? (kern + (size_t)(r + 1) * 4096)
                                                : bias)
                                  + (size_t)c * 64 + quad * 8;
                nx0 = *(const float4*)(ns);
                nx1 = *(const float4*)(ns + 4);
                ny0 = *(const float4*)(ns + 32);
                ny1 = *(const float4*)(ns + 36);
            }
            const bf16x8 a0 = *(const bf16x8*)(Ga + r * 64 + quad * 8);
            const bf16x8 a1 = *(const bf16x8*)(Ga + r * 64 + 32 + quad * 8);
            acc = __builtin_amdgcn_mfma_f32_16x16x32_bf16(a0, pack_bf8(x0, x1), acc, 0, 0, 0);
            acc = __builtin_amdgcn_mfma_f32_16x16x32_bf16(a1, pack_bf8(y0, y1), acc, 0, 0, 0);
            x0 = nx0; x1 = nx1; y0 = ny0; y1 = ny1;
        }

        // D: row = dlo + quad*4 + rr, col = c. Every out row written once.
#pragma unroll
        for (int rr = 0; rr < 4; ++rr)
            out[(size_t)(dlo + quad * 4 + rr) * ADIM + c] = acc[rr];
    }
}

extern "C" void kernel_launch(void* const* d_in, const int* in_sizes, int n_in,
                              void* d_out, int out_size, void* d_ws, size_t ws_size,
                              hipStream_t stream) {
    const float* atom = (const float*)d_in[0];
    const float* bond = (const float*)d_in[1];
    const int*   pair = (const int*)  d_in[2];
    const float* kern = (const float*)d_in[3];
    const float* bias = (const float*)d_in[4];
    float* out = (float*)d_out;

    int2* eb = (int2*)d_ws;                          // 2.29 MB buckets
    int*  cnt = (int*)((char*)d_ws + CNT_OFF);       // 17.9 KB counters

    hipMemsetAsync(cnt, 0, NSEG * sizeof(int), stream);
    scatter_kernel<<<NEDGE / 256, 256, 0, stream>>>(pair, cnt, eb);
    fused_kernel<<<NBLK, TPB, 0, stream>>>(atom, bond, cnt, eb, kern, bias, out);
}